// Round 12
// baseline (1024.081 us; speedup 1.0000x reference)
//
#include <hip/hip_runtime.h>
#include <hip/hip_bf16.h>
#include <stdint.h>

#define NU_ 100000
#define NI_ 50000
#define NN_ 150000
#define D_ 256
#define D4_ 64           // float4 per f32 row
#define DQ_ 64           // uint (4 int8 codes) per quantized row

#define NR_ 256          // item ranges for counting sort
#define IR_ 196          // items per range (ceil(50000/256))
#define TA_ 4096         // edges per pass-A tile

typedef unsigned int uint;
typedef unsigned char uchar;

// ---- int8 row-scale helpers ----
// codes biased: u8 = rint(v*127/rowmax)+128 in [1,255]; decode v=(u8-128)*step, step=rowmax/127.

__device__ __forceinline__ float wave_absmax4(float4 a) {
    float m = fmaxf(fmaxf(fabsf(a.x), fabsf(a.y)), fmaxf(fabsf(a.z), fabsf(a.w)));
#pragma unroll
    for (int off = 32; off; off >>= 1) m = fmaxf(m, __shfl_xor(m, off));
    return m;
}

__device__ __forceinline__ uint pack_q4(float4 v, float qs) {
    int c0 = (int)rintf(v.x * qs) + 128;
    int c1 = (int)rintf(v.y * qs) + 128;
    int c2 = (int)rintf(v.z * qs) + 128;
    int c3 = (int)rintf(v.w * qs) + 128;
    return (uint)c0 | ((uint)c1 << 8) | ((uint)c2 << 16) | ((uint)c3 << 24);
}

__device__ __forceinline__ void fma_q(float4& acc, float vv, uint x) {
    acc.x = fmaf(vv, (float)(x & 0xffu), acc.x);          // v_cvt_f32_ubyte0
    acc.y = fmaf(vv, (float)((x >> 8) & 0xffu), acc.y);   // v_cvt_f32_ubyte1
    acc.z = fmaf(vv, (float)((x >> 16) & 0xffu), acc.z);  // v_cvt_f32_ubyte2
    acc.w = fmaf(vv, (float)(x >> 24), acc.w);            // v_cvt_f32_ubyte3
}

// ---- int8 edge-accumulate, dr deferred, 32-bit gather offsets ----
// acc += sum_e w[c_e]*codes;  sw += sum_e w[c_e]   (caller applies dr*(acc-128*sw))
// Index as uint so the gather folds to saddr + 32-bit voffset (no 64-bit VALU chain).
__device__ __forceinline__ void edge_accum_q(const int* __restrict__ ca, int p, int end, int sub,
                                             const float* __restrict__ wsrc,
                                             const uint* __restrict__ src, uint lane,
                                             float4& acc, float& sw) {
    for (; p + 8 <= end; p += 8) {
        int c[8]; float w[8]; uint x[8];
#pragma unroll
        for (int k = 0; k < 8; ++k) c[k] = __builtin_amdgcn_readfirstlane(ca[p + k]) - sub;
#pragma unroll
        for (int k = 0; k < 8; ++k) x[k] = src[((uint)c[k] << 6) + lane];
#pragma unroll
        for (int k = 0; k < 8; ++k) w[k] = wsrc[c[k]];
#pragma unroll
        for (int k = 0; k < 8; ++k) {
            sw += w[k];
            fma_q(acc, w[k], x[k]);
        }
    }
    for (; p < end; ++p) {
        int c = __builtin_amdgcn_readfirstlane(ca[p]) - sub;
        uint x = src[((uint)c << 6) + lane];
        float w = wsrc[c];
        sw += w;
        fma_q(acc, w, x);
    }
}

__device__ __forceinline__ void quant_store(float4 acc, uint* __restrict__ dst, int r, int lane,
                                            float dr, float* __restrict__ st_arr,
                                            float* __restrict__ w_arr) {
    float m = wave_absmax4(acc);
    float qs = (m > 0.f) ? 127.0f / m : 0.0f;
    float st = m * (1.0f / 127.0f);
    dst[((uint)r << 6) + (uint)lane] = pack_q4(acc, qs);
    if (lane == 0) { st_arr[r] = st; w_arr[r] = dr * st; }
}

// ================= build1: user row_ptr (role 0) + item histogram (role 1) =================
__global__ void build1_kernel(const int* __restrict__ u, const int* __restrict__ ecols,
                              int* __restrict__ up, int* __restrict__ counts,
                              int E, int nbRowptr, int nbHist) {
    int b = blockIdx.x;
    if (b < nbRowptr) {
        int e = b * 256 + threadIdx.x;
        if (e >= E) return;
        int cur = u[e];
        int prev = (e == 0) ? -1 : u[e - 1];
        for (int r = prev + 1; r <= cur; ++r) up[r] = e;
        if (e == E - 1)
            for (int r = cur + 1; r <= NU_; ++r) up[r] = E;
    } else {
        int hb = b - nbRowptr;
        for (int i = hb * 256 + threadIdx.x; i < E; i += nbHist * 256)
            atomicAdd(&counts[ecols[i] - NU_], 1);
    }
}

// ==== build2 (blockDim=1024): scan_block | dinv_u | dinv_i ====
__global__ void build2_kernel(const int* __restrict__ counts, int* __restrict__ ip,
                              int* __restrict__ bsums, const int* __restrict__ up,
                              float* __restrict__ dinv_u, float* __restrict__ dinv_i,
                              int nbScan, int nbDu, int nbDi) {
    int b = blockIdx.x;
    int tid = threadIdx.x;
    if (b < nbScan) {
        __shared__ int sh[1024];
        int i = b * 1024 + tid;
        int v = (i < NI_) ? counts[i] : 0;
        sh[tid] = v;
        __syncthreads();
        for (int off = 1; off < 1024; off <<= 1) {
            int t = (tid >= off) ? sh[tid - off] : 0;
            __syncthreads();
            sh[tid] += t;
            __syncthreads();
        }
        if (i < NI_) ip[i] = sh[tid] - v;
        if (tid == 1023) bsums[b] = sh[1023];
        return;
    }
    b -= nbScan;
    if (b < nbDu) {
        int i = b * 1024 + tid;
        if (i < NU_) dinv_u[i] = 1.0f / sqrtf((float)(up[i + 1] - up[i]) + 1e-7f);
        return;
    }
    b -= nbDu;
    {
        int i = b * 1024 + tid;
        if (i < NI_) dinv_i[i] = 1.0f / sqrtf((float)counts[i] + 1e-7f);
    }
}

__global__ void scan_sums(int* __restrict__ bsums, int nb, int* __restrict__ ip) {
    __shared__ int sh[256];
    int tid = threadIdx.x;
    int v = (tid < nb) ? bsums[tid] : 0;
    sh[tid] = v;
    __syncthreads();
    for (int off = 1; off < 256; off <<= 1) {
        int t = (tid >= off) ? sh[tid - off] : 0;
        __syncthreads();
        sh[tid] += t;
        __syncthreads();
    }
    if (tid < nb) bsums[tid] = sh[tid] - v;
    if (tid == 255) ip[NI_] = sh[255];
}

// scan_add + rcur init (rcur[q] = final ip at range starts)
__global__ void scan_add(int* __restrict__ ip, const int* __restrict__ bsums,
                         int* __restrict__ rcur) {
    int i = blockIdx.x * 1024 + threadIdx.x;
    if (i < NI_) {
        int s = ip[i] + bsums[i >> 10];
        ip[i] = s;
        int q = i / IR_;
        if (i == q * IR_) rcur[q] = s;
    }
}

// ========= fillA_quant: fillA (LDS-binned coarse scatter) | quant(Xu0) | quant(Xi0) =========
__global__ __launch_bounds__(256) void fillA_quant_kernel(
    const int* __restrict__ u_arr, const int* __restrict__ ecols,
    int* __restrict__ rcur, uint* __restrict__ staging, int E, int nfa,
    const float* __restrict__ user_emb, const float* __restrict__ item_emb,
    const float* __restrict__ dinv_u, const float* __restrict__ dinv_i,
    uint* __restrict__ Xu0, float* __restrict__ st0u, float* __restrict__ w0u,
    uint* __restrict__ Xi0, float* __restrict__ st0i, float* __restrict__ w0i,
    int nbQU)
{
    __shared__ uint vals[TA_];
    __shared__ uchar rng[TA_];
    __shared__ int hist[NR_];
    __shared__ int resv[NR_];
    int b = blockIdx.x;
    int tid = threadIdx.x;
    if (b < nfa) {
        // ---- fillA role ----
        int lo = b * TA_;
        int n = E - lo; if (n > TA_) n = TA_;
        if (tid < NR_) hist[tid] = 0;
        __syncthreads();
        for (int i = tid; i < n; i += 256) {
            int it = ecols[lo + i] - NU_;
            int uu = u_arr[lo + i];
            int r = it / IR_;
            int itl = it - r * IR_;
            vals[i] = (uint)uu | ((uint)itl << 17);
            rng[i] = (uchar)r;
            atomicAdd(&hist[r], 1);
        }
        __syncthreads();
        if (tid < NR_) {
            int c = hist[tid];
            resv[tid] = (c > 0) ? atomicAdd(&rcur[tid], c) : 0;
        }
        __syncthreads();
        if (tid < NR_) hist[tid] = 0;
        __syncthreads();
        for (int i = tid; i < n; i += 256) {
            int r = rng[i];
            int rank = atomicAdd(&hist[r], 1);
            staging[resv[r] + rank] = vals[i];
        }
        return;
    }
    b -= nfa;
    int lane = tid & 63;
    int wv = tid >> 6;
    if (b < nbQU) {
        int r = b * 4 + wv;
        if (r >= NU_) return;
        float4 v = ((const float4*)(user_emb + (size_t)r * D_))[lane];
        quant_store(v, Xu0, r, lane, dinv_u[r], st0u, w0u);
        return;
    }
    b -= nbQU;
    {
        int r = b * 4 + wv;
        if (r >= NI_) return;
        float4 v = ((const float4*)(item_emb + (size_t)r * D_))[lane];
        quant_store(v, Xi0, r, lane, dinv_i[r], st0i, w0i);
    }
}

// ================= fill pass B: per-range fine scatter =================
__global__ __launch_bounds__(256) void fillB_kernel(
    const uint* __restrict__ staging, const int* __restrict__ ip, int* __restrict__ icol)
{
    __shared__ int cur[IR_];
    int r = blockIdx.x;
    int tid = threadIdx.x;
    int ibase = r * IR_;
    int iend = ibase + IR_; if (iend > NI_) iend = NI_;
    int nIt = iend - ibase;
    if (tid < nIt) cur[tid] = ip[ibase + tid];
    __syncthreads();
    int lo = ip[ibase];
    int hi = ip[iend];
    for (int p = lo + tid; p < hi; p += 256) {
        uint v = staging[p];
        int uu = (int)(v & 0x1FFFFu);
        int itl = (int)(v >> 17);
        int slot = atomicAdd(&cur[itl], 1);
        icol[slot] = uu;
    }
}

// ================= megaL1: acc_init+ego | full spmm L1 (both dirs, int8) =================
__global__ __launch_bounds__(256) void megaL1_kernel(
    const int* __restrict__ up, const int* __restrict__ ecols,
    const int* __restrict__ ip, const int* __restrict__ icol,
    const float* __restrict__ dinv_u, const float* __restrict__ dinv_i,
    const uint* __restrict__ Xu0, const float* __restrict__ w0u,
    const uint* __restrict__ Xi0, const float* __restrict__ w0i,
    uint* __restrict__ Yu1, float* __restrict__ st1u, float* __restrict__ w1u,
    uint* __restrict__ Yi1, float* __restrict__ st1i, float* __restrict__ w1i,
    const float* __restrict__ user_emb, const float* __restrict__ item_emb,
    const int* __restrict__ uId, const int* __restrict__ iId, const int* __restrict__ nId,
    float* __restrict__ accs, float* __restrict__ out_ego, int Bn, int accBlocks)
{
    int b = blockIdx.x;
    uint lane = threadIdx.x & 63;
    int wave = threadIdx.x >> 6;
    if (b < accBlocks) {
        int rowId = b * 4 + wave;
        if (rowId >= 3 * Bn) return;
        int s = rowId / Bn;
        int j = rowId - s * Bn;
        const float* src;
        if (s == 0)      src = user_emb + (size_t)uId[j] * D_;
        else if (s == 1) src = item_emb + (size_t)iId[j] * D_;
        else             src = item_emb + (size_t)nId[j] * D_;
        float4 x = ((const float4*)src)[lane];
        ((float4*)accs)[(size_t)rowId * D4_ + lane] = x;
        ((float4*)out_ego)[(size_t)rowId * D4_ + lane] = x;
        return;
    }
    int row = (b - accBlocks) * 4 + wave;
    if (row >= NN_) return;
    float4 acc = make_float4(0.f, 0.f, 0.f, 0.f);
    float sw = 0.f;
    if (row < NU_) {
        int r = row;
        int p   = __builtin_amdgcn_readfirstlane(up[r]);
        int end = __builtin_amdgcn_readfirstlane(up[r + 1]);
        float dr = dinv_u[r];
        edge_accum_q(ecols, p, end, NU_, w0i, Xi0, lane, acc, sw);
        float c = 128.f * sw;
        acc.x = dr * (acc.x - c); acc.y = dr * (acc.y - c);
        acc.z = dr * (acc.z - c); acc.w = dr * (acc.w - c);
        quant_store(acc, Yu1, r, lane, dr, st1u, w1u);
    } else {
        int r = row - NU_;
        int p   = __builtin_amdgcn_readfirstlane(ip[r]);
        int end = __builtin_amdgcn_readfirstlane(ip[r + 1]);
        float dr = dinv_i[r];
        edge_accum_q(icol, p, end, 0, w0u, Xu0, lane, acc, sw);
        float c = 128.f * sw;
        acc.x = dr * (acc.x - c); acc.y = dr * (acc.y - c);
        acc.z = dr * (acc.z - c); acc.w = dr * (acc.w - c);
        quant_store(acc, Yi1, r, lane, dr, st1i, w1i);
    }
}

// ================= mega2: acc-gather(Z1) | full spmm L2 (both dirs, int8) =================
__global__ __launch_bounds__(256) void mega2_kernel(
    const int* __restrict__ up, const int* __restrict__ ecols,
    const int* __restrict__ ip, const int* __restrict__ icol,
    const float* __restrict__ dinv_u, const float* __restrict__ dinv_i,
    const uint* __restrict__ Xu1, const float* __restrict__ st1u, const float* __restrict__ w1u,
    const uint* __restrict__ Xi1, const float* __restrict__ st1i, const float* __restrict__ w1i,
    uint* __restrict__ Yu2, float* __restrict__ st2u, float* __restrict__ w2u,
    uint* __restrict__ Yi2, float* __restrict__ st2i, float* __restrict__ w2i,
    const int* __restrict__ uId, const int* __restrict__ iId, const int* __restrict__ nId,
    float* __restrict__ accs, int Bn, int accBlocks)
{
    int b = blockIdx.x;
    uint lane = threadIdx.x & 63;
    int wave = threadIdx.x >> 6;
    if (b < accBlocks) {
        int rowId = b * 4 + wave;
        if (rowId >= 3 * Bn) return;
        int s = rowId / Bn;
        int j = rowId - s * Bn;
        uint x; float st;
        if (s == 0)      { int n = uId[j]; x = Xu1[((uint)n << 6) + lane]; st = st1u[n]; }
        else if (s == 1) { int n = iId[j]; x = Xi1[((uint)n << 6) + lane]; st = st1i[n]; }
        else             { int n = nId[j]; x = Xi1[((uint)n << 6) + lane]; st = st1i[n]; }
        float4* a = (float4*)accs + (size_t)rowId * D4_ + lane;
        float4 t = *a;
        t.x += st * ((float)(x & 0xffu) - 128.f);
        t.y += st * ((float)((x >> 8) & 0xffu) - 128.f);
        t.z += st * ((float)((x >> 16) & 0xffu) - 128.f);
        t.w += st * ((float)(x >> 24) - 128.f);
        *a = t;
        return;
    }
    int row = (b - accBlocks) * 4 + wave;
    if (row >= NN_) return;
    float4 acc = make_float4(0.f, 0.f, 0.f, 0.f);
    float sw = 0.f;
    if (row < NU_) {
        int r = row;
        int p   = __builtin_amdgcn_readfirstlane(up[r]);
        int end = __builtin_amdgcn_readfirstlane(up[r + 1]);
        float dr = dinv_u[r];
        edge_accum_q(ecols, p, end, NU_, w1i, Xi1, lane, acc, sw);
        float c = 128.f * sw;
        acc.x = dr * (acc.x - c); acc.y = dr * (acc.y - c);
        acc.z = dr * (acc.z - c); acc.w = dr * (acc.w - c);
        quant_store(acc, Yu2, r, lane, dr, st2u, w2u);
    } else {
        int r = row - NU_;
        int p   = __builtin_amdgcn_readfirstlane(ip[r]);
        int end = __builtin_amdgcn_readfirstlane(ip[r + 1]);
        float dr = dinv_i[r];
        edge_accum_q(icol, p, end, 0, w1u, Xu1, lane, acc, sw);
        float c = 128.f * sw;
        acc.x = dr * (acc.x - c); acc.y = dr * (acc.y - c);
        acc.z = dr * (acc.z - c); acc.w = dr * (acc.w - c);
        quant_store(acc, Yi2, r, lane, dr, st2i, w2i);
    }
}

// ================= sampled layer-3 + Z2 self, folded into acc =================
__global__ __launch_bounds__(256) void sampled3_kernel(
    const int* __restrict__ up, const int* __restrict__ ecols,
    const int* __restrict__ ip, const int* __restrict__ icol,
    const float* __restrict__ dinv_u, const float* __restrict__ dinv_i,
    const uint* __restrict__ Xu2, const float* __restrict__ st2u, const float* __restrict__ w2u,
    const uint* __restrict__ Xi2, const float* __restrict__ st2i, const float* __restrict__ w2i,
    const int* __restrict__ uId, const int* __restrict__ iId, const int* __restrict__ nId,
    float* __restrict__ accs, int Bn)
{
    uint lane = threadIdx.x & 63;
    int rowId = blockIdx.x * 4 + (threadIdx.x >> 6);
    if (rowId >= 3 * Bn) return;
    int s = rowId / Bn;
    int j = rowId - s * Bn;
    float4 acc = make_float4(0.f, 0.f, 0.f, 0.f);
    float sw = 0.f;
    uint self; float selfst; float dr;
    if (s == 0) {
        int n = uId[j];
        self = Xu2[((uint)n << 6) + lane]; selfst = st2u[n];
        int p   = __builtin_amdgcn_readfirstlane(up[n]);
        int end = __builtin_amdgcn_readfirstlane(up[n + 1]);
        dr = dinv_u[n];
        edge_accum_q(ecols, p, end, NU_, w2i, Xi2, lane, acc, sw);
    } else {
        int n = (s == 1) ? iId[j] : nId[j];
        self = Xi2[((uint)n << 6) + lane]; selfst = st2i[n];
        int p   = __builtin_amdgcn_readfirstlane(ip[n]);
        int end = __builtin_amdgcn_readfirstlane(ip[n + 1]);
        dr = dinv_i[n];
        edge_accum_q(icol, p, end, 0, w2u, Xu2, lane, acc, sw);
    }
    float c = 128.f * sw;
    float4* a = (float4*)accs + (size_t)rowId * D4_ + lane;
    float4 t = *a;
    t.x += dr * (acc.x - c) + selfst * ((float)(self & 0xffu) - 128.f);
    t.y += dr * (acc.y - c) + selfst * ((float)((self >> 8) & 0xffu) - 128.f);
    t.z += dr * (acc.z - c) + selfst * ((float)((self >> 16) & 0xffu) - 128.f);
    t.w += dr * (acc.w - c) + selfst * ((float)(self >> 24) - 128.f);
    *a = t;
}

// ================= scores =================
__global__ void scores_kernel(const float* __restrict__ acc, float* __restrict__ out_pos,
                              float* __restrict__ out_neg, int Bn) {
    int j = blockIdx.x * 4 + (threadIdx.x >> 6);
    int lane = threadIdx.x & 63;
    if (j >= Bn) return;
    const float4* u = (const float4*)acc + (size_t)j * D4_;
    const float4* p = (const float4*)(acc + (size_t)Bn * D_) + (size_t)j * D4_;
    const float4* n = (const float4*)(acc + (size_t)2 * Bn * D_) + (size_t)j * D4_;
    float4 uu = u[lane], pp = p[lane], nn = n[lane];
    float dp = uu.x * pp.x + uu.y * pp.y + uu.z * pp.z + uu.w * pp.w;
    float dn = uu.x * nn.x + uu.y * nn.y + uu.z * nn.z + uu.w * nn.w;
    for (int off = 32; off; off >>= 1) {
        dp += __shfl_xor(dp, off);
        dn += __shfl_xor(dn, off);
    }
    if (lane == 0) {
        out_pos[j] = dp * (1.0f / 16.0f);   // (1/4)^2
        out_neg[j] = dn * (1.0f / 16.0f);
    }
}

// ================= launch =================
extern "C" void kernel_launch(void* const* d_in, const int* in_sizes, int n_in,
                              void* d_out, int out_size, void* d_ws, size_t ws_size,
                              hipStream_t stream) {
    const float* user_emb = (const float*)d_in[0];
    const float* item_emb = (const float*)d_in[1];
    const int*   rows     = (const int*)d_in[3];   // rows[0:E] = u (sorted)
    const int*   cols     = (const int*)d_in[4];   // cols[0:E] = it + NU
    const int*   userId   = (const int*)d_in[5];
    const int*   itemId   = (const int*)d_in[6];
    const int*   negId    = (const int*)d_in[7];
    int nnz = in_sizes[3];
    int E   = nnz / 2;
    int Bn  = in_sizes[5];

    const int* u_arr = rows;
    const int* ecols = cols;

    uint8_t* ws = (uint8_t*)d_ws;
    size_t off = 0;
    auto alloc = [&](size_t bytes) -> void* {
        void* p = ws + off;
        off += (bytes + 255) & ~(size_t)255;
        return p;
    };
    int*   up      = (int*)alloc((size_t)(NU_ + 1) * sizeof(int));
    int*   ip      = (int*)alloc((size_t)(NI_ + 1) * sizeof(int));
    int*   counts  = (int*)alloc((size_t)NI_ * sizeof(int));
    int*   bsums   = (int*)alloc(256 * sizeof(int));
    int*   rcur    = (int*)alloc(NR_ * sizeof(int));
    float* dinv_u  = (float*)alloc((size_t)NU_ * sizeof(float));
    float* dinv_i  = (float*)alloc((size_t)NI_ * sizeof(float));
    int*   icol    = (int*)alloc((size_t)E * sizeof(int));
    uint*  staging = (uint*)alloc((size_t)E * sizeof(uint));
    uint*  XuA     = (uint*)alloc((size_t)NU_ * DQ_ * sizeof(uint));   // Xu0, then Z2u
    uint*  XuB     = (uint*)alloc((size_t)NU_ * DQ_ * sizeof(uint));   // Z1u
    uint*  XiA     = (uint*)alloc((size_t)NI_ * DQ_ * sizeof(uint));   // Xi0, then Z2i
    uint*  XiB     = (uint*)alloc((size_t)NI_ * DQ_ * sizeof(uint));   // Z1i
    float* w0u     = (float*)alloc((size_t)NU_ * sizeof(float));
    float* w0i     = (float*)alloc((size_t)NI_ * sizeof(float));
    float* st0u    = (float*)alloc((size_t)NU_ * sizeof(float));
    float* st0i    = (float*)alloc((size_t)NI_ * sizeof(float));
    float* st1u    = (float*)alloc((size_t)NU_ * sizeof(float));
    float* w1u     = (float*)alloc((size_t)NU_ * sizeof(float));
    float* st1i    = (float*)alloc((size_t)NI_ * sizeof(float));
    float* w1i     = (float*)alloc((size_t)NI_ * sizeof(float));
    float* st2u    = (float*)alloc((size_t)NU_ * sizeof(float));
    float* w2u     = (float*)alloc((size_t)NU_ * sizeof(float));
    float* st2i    = (float*)alloc((size_t)NI_ * sizeof(float));
    float* w2i     = (float*)alloc((size_t)NI_ * sizeof(float));
    float* accs    = (float*)alloc((size_t)3 * Bn * D_ * sizeof(float));

    float* out_pos = (float*)d_out;
    float* out_neg = out_pos + Bn;
    float* out_ego = out_neg + Bn;

    int accBlocks = (3 * Bn + 3) / 4;   // 3072 for B=4096

    // --- build phase ---
    (void)hipMemsetAsync(counts, 0, (size_t)NI_ * sizeof(int), stream);
    int nbRowptr = (E + 255) / 256;
    int nbHist = 2048;
    build1_kernel<<<nbRowptr + nbHist, 256, 0, stream>>>(u_arr, ecols, up, counts, E, nbRowptr, nbHist);

    int nbScan = (NI_ + 1023) / 1024;      // 49
    int nbDu   = (NU_ + 1023) / 1024;      // 98
    int nbDi   = (NI_ + 1023) / 1024;      // 49
    build2_kernel<<<nbScan + nbDu + nbDi, 1024, 0, stream>>>(
        counts, ip, bsums, up, dinv_u, dinv_i, nbScan, nbDu, nbDi);
    scan_sums<<<1, 256, 0, stream>>>(bsums, nbScan, ip);
    scan_add<<<nbScan, 1024, 0, stream>>>(ip, bsums, rcur);

    // --- fillA + quant(Xu0,Xi0) fused ---
    int nfa  = (E + TA_ - 1) / TA_;
    int nbQU = (NU_ + 3) / 4;              // 25000
    int nbQI = (NI_ + 3) / 4;              // 12500
    fillA_quant_kernel<<<nfa + nbQU + nbQI, 256, 0, stream>>>(
        u_arr, ecols, rcur, staging, E, nfa,
        user_emb, item_emb, dinv_u, dinv_i,
        XuA, st0u, w0u, XiA, st0i, w0i, nbQU);

    // --- fillB ---
    fillB_kernel<<<NR_, 256, 0, stream>>>(staging, ip, icol);

    // --- L1: acc_init + full spmm (X0 -> Z1 = XuB,XiB) ---
    int spmmBlocks = (NN_ + 3) / 4;
    megaL1_kernel<<<accBlocks + spmmBlocks, 256, 0, stream>>>(
        up, ecols, ip, icol, dinv_u, dinv_i,
        XuA, w0u, XiA, w0i,
        XuB, st1u, w1u, XiB, st1i, w1i,
        user_emb, item_emb, userId, itemId, negId, accs, out_ego, Bn, accBlocks);

    // --- L2: acc-gather(Z1) + full spmm (Z1 -> Z2 = XuA,XiA) ---
    mega2_kernel<<<accBlocks + spmmBlocks, 256, 0, stream>>>(
        up, ecols, ip, icol, dinv_u, dinv_i,
        XuB, st1u, w1u, XiB, st1i, w1i,
        XuA, st2u, w2u, XiA, st2i, w2i,
        userId, itemId, negId, accs, Bn, accBlocks);

    // --- sampled layer-3 + Z2 self ---
    sampled3_kernel<<<accBlocks, 256, 0, stream>>>(
        up, ecols, ip, icol, dinv_u, dinv_i,
        XuA, st2u, w2u, XiA, st2i, w2i,
        userId, itemId, negId, accs, Bn);

    // --- scores ---
    scores_kernel<<<(Bn + 3) / 4, 256, 0, stream>>>(accs, out_pos, out_neg, Bn);
}